// Round 15
// baseline (208.176 us; speedup 1.0000x reference)
//
#include <hip/hip_runtime.h>
#include <math.h>

#define NUM_GRAPHS 1024
#define NUM_FEAT 128
#define EPS 1e-5f
#define BT 512                 // 16 row-groups of 32 lanes; 8 waves
#define NGRP 16                // BT/32
#define LDS_ROWS 312           // fp16 rows in LDS = 78 KiB -> 2 blocks/CU still fit (156<=160)
#define RK 30                  // fp16 rows per group in registers (60 VGPRs)
#define REG_ROWS (RK * NGRP)   // 480
#define TILE_ROWS (LDS_ROWS + REG_ROWS)  // 792 single-touch rows; rest streams via L3

typedef float f4 __attribute__((ext_vector_type(4)));
typedef __fp16 h2 __attribute__((ext_vector_type(2)));   // cvt_pkrtz return type

// ws layout (ints): [0,1024) gstart | [1024,2048) gend
__global__ void init_bounds_kernel(int* gstart, int* gend) {
    int g = blockIdx.x * blockDim.x + threadIdx.x;
    if (g < NUM_GRAPHS) { gstart[g] = 0; gend[g] = 0; }  // empty graphs -> [0,0)
}

__global__ void find_bounds_kernel(const int* __restrict__ batch, int n_rows,
                                   int* __restrict__ gstart, int* __restrict__ gend) {
    int r = blockIdx.x * blockDim.x + threadIdx.x;
    if (r >= n_rows) return;
    int g = batch[r];
    if (r == 0 || batch[r - 1] != g) gstart[g] = r;
    if (r == n_rows - 1 || batch[r + 1] != g) gend[g] = r + 1;
}

#define LOADX(r)    (reinterpret_cast<const f4*>(x + (size_t)(r) * NUM_FEAT)[lane32])
#define LOADX_NT(r) __builtin_nontemporal_load(&reinterpret_cast<const f4*>(x + (size_t)(r) * NUM_FEAT)[lane32])
#define ROWSTAT(v, kparity)                                                             \
    do {                                                                                \
        const float rs_  = (v).x + (v).y + (v).z + (v).w;                               \
        const float rss_ = fmaf((v).x, (v).x, fmaf((v).y, (v).y,                        \
                           fmaf((v).z, (v).z, (v).w * (v).w)));                         \
        if (kparity) { as1 = fmaf(m, rs_, as1); ass1 = fmaf(m, rss_, ass1); }           \
        else         { as0 = fmaf(m, rs_, as0); ass0 = fmaf(m, rss_, ass0); }           \
    } while (0)

// Hybrid single-touch GraphNorm (round-13/14 structure, max coverage).
// Constraints learned rounds 4-14: (a) 2 blocks/CU is the ~6.7 TB/s regime;
// (b) VGPR allocator grants <=128/wave - stay under or it spills; (c) LDS
// pool 160 KiB/CU shared by the 2 blocks. 78 KiB LDS (312 rows) + 60-VGPR
// reg tile (480 rows) = 792 rows single-touch; remaining ~19% of each graph
// streams with the L3-reuse re-read. Fabric ~1.12 GB.
__global__ __launch_bounds__(BT)
void fused_kernel(const float* __restrict__ x,
                  const float* __restrict__ weight,
                  const float* __restrict__ bias,
                  const int* __restrict__ gstart,
                  const int* __restrict__ gend,
                  float* __restrict__ out) {
    __shared__ h2 tile[LDS_ROWS * 64];   // [row][lo-plane 0..31 | hi-plane 32..63]
    __shared__ float lsum, lss;

    const int lane32 = threadIdx.x & 31;
    const int grp    = threadIdx.x >> 5;   // 0..15

    const int g = blockIdx.x;              // one graph per block
    const int s = gstart[g];
    const int e = gend[g];
    if (s >= e) return;                    // uniform across block

    if (threadIdx.x == 0) { lsum = 0.0f; lss = 0.0f; }
    __syncthreads();

    const f4 w = reinterpret_cast<const f4*>(weight)[lane32];
    const f4 b = reinterpret_cast<const f4*>(bias)[lane32];

    float as0 = 0.0f, ass0 = 0.0f, as1 = 0.0f, ass1 = 0.0f;

    // ---- sweep 1a: rows [s, s+312) -> LDS fp16 tile (NT: single HBM touch) ----
    // 312 = 19*16 + 8: first 19 full iterations + one half iteration (grp<8)
    #pragma unroll
    for (int j = 0; j < 19; ++j) {
        const int slot = j * NGRP + grp;
        const int rr = s + slot;
        const bool valid = rr < e;
        const int r = valid ? rr : (e - 1);
        const float m = valid ? 1.0f : 0.0f;
        const f4 v = LOADX_NT(r);
        tile[slot * 64 + lane32]      = __builtin_amdgcn_cvt_pkrtz(v.x, v.y);
        tile[slot * 64 + 32 + lane32] = __builtin_amdgcn_cvt_pkrtz(v.z, v.w);
        ROWSTAT(v, j & 1);
    }
    if (grp < 8) {   // rows 304..311; wave-uniform branch (grp uniform per wave)
        const int slot = 19 * NGRP + grp;
        const int rr = s + slot;
        const bool valid = rr < e;
        const int r = valid ? rr : (e - 1);
        const float m = valid ? 1.0f : 0.0f;
        const f4 v = LOADX_NT(r);
        tile[slot * 64 + lane32]      = __builtin_amdgcn_cvt_pkrtz(v.x, v.y);
        tile[slot * 64 + 32 + lane32] = __builtin_amdgcn_cvt_pkrtz(v.z, v.w);
        ROWSTAT(v, 1);
    }

    // ---- sweep 1b: rows [s+312, s+792) -> fp16 register tile ----
    h2 hv[2 * RK];                         // 60 VGPRs
    const int rbase = s + LDS_ROWS + grp;
    #pragma unroll
    for (int k = 0; k < RK; ++k) {
        const int rr = rbase + k * NGRP;
        const bool valid = rr < e;
        const int r = valid ? rr : (e - 1);
        const float m = valid ? 1.0f : 0.0f;
        const f4 v = LOADX_NT(r);
        hv[2 * k]     = __builtin_amdgcn_cvt_pkrtz(v.x, v.y);
        hv[2 * k + 1] = __builtin_amdgcn_cvt_pkrtz(v.z, v.w);
        ROWSTAT(v, k & 1);
    }

    // ---- sweep 1c: rows [s+792, e) streamed (PLAIN loads -> L3 for re-read) ----
    {
        const float m = 1.0f;
        int r = s + TILE_ROWS + grp;
        for (; r + 3 * NGRP < e; r += 4 * NGRP) {
            const f4 v0 = LOADX(r);
            const f4 v1 = LOADX(r + NGRP);
            const f4 v2 = LOADX(r + 2 * NGRP);
            const f4 v3 = LOADX(r + 3 * NGRP);
            ROWSTAT(v0, 0); ROWSTAT(v1, 1); ROWSTAT(v2, 0); ROWSTAT(v3, 1);
        }
        for (; r < e; r += NGRP) {
            const f4 v = LOADX(r);
            ROWSTAT(v, 0);
        }
    }

    float as = as0 + as1, ass = ass0 + ass1;
    #pragma unroll
    for (int off = 16; off > 0; off >>= 1) {
        as  += __shfl_down(as,  off, 32);
        ass += __shfl_down(ass, off, 32);
    }
    if (lane32 == 0) {
        atomicAdd(&lsum, as);
        atomicAdd(&lss,  ass);
    }
    __syncthreads();

    // stats computed redundantly by every thread
    const float denom = (float)(e - s) * (float)NUM_FEAT;
    const float mean  = lsum / denom;
    const float var   = fmaxf(lss / denom - mean * mean, 0.0f);
    const float inv   = rsqrtf(var + EPS);
    const float mi    = mean * inv;        // o = w*(v*inv - mi) + b

    // ---- sweep 2a: normalize LDS rows, NT stream out ----
    #pragma unroll
    for (int j = 0; j < 19; ++j) {
        const int slot = j * NGRP + grp;
        const int rr = s + slot;
        const int r = (rr < e) ? rr : (e - 1);   // clamped dup writes = same bytes
        const h2 a = tile[slot * 64 + lane32];
        const h2 c = tile[slot * 64 + 32 + lane32];
        f4 o;
        o.x = fmaf(w.x, fmaf((float)a.x, inv, -mi), b.x);
        o.y = fmaf(w.y, fmaf((float)a.y, inv, -mi), b.y);
        o.z = fmaf(w.z, fmaf((float)c.x, inv, -mi), b.z);
        o.w = fmaf(w.w, fmaf((float)c.y, inv, -mi), b.w);
        __builtin_nontemporal_store(
            o, &reinterpret_cast<f4*>(out + (size_t)r * NUM_FEAT)[lane32]);
    }
    if (grp < 8) {
        const int slot = 19 * NGRP + grp;
        const int rr = s + slot;
        const int r = (rr < e) ? rr : (e - 1);
        const h2 a = tile[slot * 64 + lane32];
        const h2 c = tile[slot * 64 + 32 + lane32];
        f4 o;
        o.x = fmaf(w.x, fmaf((float)a.x, inv, -mi), b.x);
        o.y = fmaf(w.y, fmaf((float)a.y, inv, -mi), b.y);
        o.z = fmaf(w.z, fmaf((float)c.x, inv, -mi), b.z);
        o.w = fmaf(w.w, fmaf((float)c.y, inv, -mi), b.w);
        __builtin_nontemporal_store(
            o, &reinterpret_cast<f4*>(out + (size_t)r * NUM_FEAT)[lane32]);
    }

    // ---- sweep 2b: normalize register rows ----
    #pragma unroll
    for (int k = 0; k < RK; ++k) {
        const int rr = rbase + k * NGRP;
        const int r = (rr < e) ? rr : (e - 1);
        const h2 a = hv[2 * k];
        const h2 c = hv[2 * k + 1];
        f4 o;
        o.x = fmaf(w.x, fmaf((float)a.x, inv, -mi), b.x);
        o.y = fmaf(w.y, fmaf((float)a.y, inv, -mi), b.y);
        o.z = fmaf(w.z, fmaf((float)c.x, inv, -mi), b.z);
        o.w = fmaf(w.w, fmaf((float)c.y, inv, -mi), b.w);
        __builtin_nontemporal_store(
            o, &reinterpret_cast<f4*>(out + (size_t)r * NUM_FEAT)[lane32]);
    }

    // ---- sweep 2c: streamed rows re-read from L3 (plain), fp32 exact ----
    {
        int r = s + TILE_ROWS + grp;
        for (; r + 3 * NGRP < e; r += 4 * NGRP) {
            const f4 v0 = LOADX(r);
            const f4 v1 = LOADX(r + NGRP);
            const f4 v2 = LOADX(r + 2 * NGRP);
            const f4 v3 = LOADX(r + 3 * NGRP);
            f4 o0, o1, o2, o3;
            o0.x = fmaf(w.x, fmaf(v0.x, inv, -mi), b.x);
            o0.y = fmaf(w.y, fmaf(v0.y, inv, -mi), b.y);
            o0.z = fmaf(w.z, fmaf(v0.z, inv, -mi), b.z);
            o0.w = fmaf(w.w, fmaf(v0.w, inv, -mi), b.w);
            o1.x = fmaf(w.x, fmaf(v1.x, inv, -mi), b.x);
            o1.y = fmaf(w.y, fmaf(v1.y, inv, -mi), b.y);
            o1.z = fmaf(w.z, fmaf(v1.z, inv, -mi), b.z);
            o1.w = fmaf(w.w, fmaf(v1.w, inv, -mi), b.w);
            o2.x = fmaf(w.x, fmaf(v2.x, inv, -mi), b.x);
            o2.y = fmaf(w.y, fmaf(v2.y, inv, -mi), b.y);
            o2.z = fmaf(w.z, fmaf(v2.z, inv, -mi), b.z);
            o2.w = fmaf(w.w, fmaf(v2.w, inv, -mi), b.w);
            o3.x = fmaf(w.x, fmaf(v3.x, inv, -mi), b.x);
            o3.y = fmaf(w.y, fmaf(v3.y, inv, -mi), b.y);
            o3.z = fmaf(w.z, fmaf(v3.z, inv, -mi), b.z);
            o3.w = fmaf(w.w, fmaf(v3.w, inv, -mi), b.w);
            __builtin_nontemporal_store(o0, &reinterpret_cast<f4*>(out + (size_t)r * NUM_FEAT)[lane32]);
            __builtin_nontemporal_store(o1, &reinterpret_cast<f4*>(out + (size_t)(r + NGRP) * NUM_FEAT)[lane32]);
            __builtin_nontemporal_store(o2, &reinterpret_cast<f4*>(out + (size_t)(r + 2 * NGRP) * NUM_FEAT)[lane32]);
            __builtin_nontemporal_store(o3, &reinterpret_cast<f4*>(out + (size_t)(r + 3 * NGRP) * NUM_FEAT)[lane32]);
        }
        for (; r < e; r += NGRP) {
            const f4 v = LOADX(r);
            f4 o;
            o.x = fmaf(w.x, fmaf(v.x, inv, -mi), b.x);
            o.y = fmaf(w.y, fmaf(v.y, inv, -mi), b.y);
            o.z = fmaf(w.z, fmaf(v.z, inv, -mi), b.z);
            o.w = fmaf(w.w, fmaf(v.w, inv, -mi), b.w);
            __builtin_nontemporal_store(
                o, &reinterpret_cast<f4*>(out + (size_t)r * NUM_FEAT)[lane32]);
        }
    }
}

extern "C" void kernel_launch(void* const* d_in, const int* in_sizes, int n_in,
                              void* d_out, int out_size, void* d_ws, size_t ws_size,
                              hipStream_t stream) {
    const float* x      = (const float*)d_in[0];
    const int*   batch  = (const int*)d_in[1];
    const float* weight = (const float*)d_in[2];
    const float* bias   = (const float*)d_in[3];
    float* out = (float*)d_out;

    const int n_rows = in_sizes[1];  // NUM_NODES

    int* gstart = (int*)d_ws;
    int* gend   = gstart + NUM_GRAPHS;

    init_bounds_kernel<<<(NUM_GRAPHS + 255) / 256, 256, 0, stream>>>(gstart, gend);
    find_bounds_kernel<<<(n_rows + 255) / 256, 256, 0, stream>>>(batch, n_rows,
                                                                 gstart, gend);
    fused_kernel<<<NUM_GRAPHS, BT, 0, stream>>>(x, weight, bias, gstart, gend, out);
}

// Round 16
// 189.327 us; speedup vs baseline: 1.0996x; 1.0996x over previous
//
#include <hip/hip_runtime.h>
#include <math.h>

#define NUM_GRAPHS 1024
#define NUM_FEAT 128
#define EPS 1e-5f
#define BT 512                 // 16 row-groups of 32 lanes; 8 waves
#define NGRP 16                // BT/32
#define LDS_ROWS 304           // fp16 rows in LDS = 76 KiB -> 2 blocks/CU (153<160, slack kept)
#define LDS_IT (LDS_ROWS / NGRP)   // 19
#define RK 26                  // fp16 rows per group in registers (52 VGPRs)
#define REG_ROWS (RK * NGRP)   // 416
#define TILE_ROWS (LDS_ROWS + REG_ROWS)  // 720 single-touch rows; rest streams via L3

typedef float f4 __attribute__((ext_vector_type(4)));
typedef __fp16 h2 __attribute__((ext_vector_type(2)));   // cvt_pkrtz return type

// ws layout (ints): [0,1024) gstart | [1024,2048) gend
__global__ void init_bounds_kernel(int* gstart, int* gend) {
    int g = blockIdx.x * blockDim.x + threadIdx.x;
    if (g < NUM_GRAPHS) { gstart[g] = 0; gend[g] = 0; }  // empty graphs -> [0,0)
}

__global__ void find_bounds_kernel(const int* __restrict__ batch, int n_rows,
                                   int* __restrict__ gstart, int* __restrict__ gend) {
    int r = blockIdx.x * blockDim.x + threadIdx.x;
    if (r >= n_rows) return;
    int g = batch[r];
    if (r == 0 || batch[r - 1] != g) gstart[g] = r;
    if (r == n_rows - 1 || batch[r + 1] != g) gend[g] = r + 1;
}

#define LOADX(r)    (reinterpret_cast<const f4*>(x + (size_t)(r) * NUM_FEAT)[lane32])
#define LOADX_NT(r) __builtin_nontemporal_load(&reinterpret_cast<const f4*>(x + (size_t)(r) * NUM_FEAT)[lane32])
#define ROWSTAT(v, kparity)                                                             \
    do {                                                                                \
        const float rs_  = (v).x + (v).y + (v).z + (v).w;                               \
        const float rss_ = fmaf((v).x, (v).x, fmaf((v).y, (v).y,                        \
                           fmaf((v).z, (v).z, (v).w * (v).w)));                         \
        if (kparity) { as1 = fmaf(m, rs_, as1); ass1 = fmaf(m, rss_, ass1); }           \
        else         { as0 = fmaf(m, rs_, as0); ass0 = fmaf(m, rss_, ass0); }           \
    } while (0)

// Hybrid single-touch GraphNorm — the ROUND-14 OPTIMUM, reverted after round
// 15's coverage push regressed (capacity cliffs: 78KiB LDS/block breaks
// 2-block/CU co-residency at the 160KiB pool; RK=30 risks the 128-VGPR
// allocator grant). Measured constraints (rounds 4-15):
//   (a) 2 blocks/CU is the ~6.7 TB/s execution regime; 1 block/CU = 2.9-4.4.
//   (b) VGPR allocator grants <=128/wave here; bigger tiles spill to scratch.
//   (c) LDS tile is fabric-free; 76KiB/block keeps 2 blocks resident.
// 304 LDS rows + 416 reg rows = 720 single-touch; remaining ~26% streams
// with the L3-reuse re-read. Fabric ~1.16GB -> ~190us total (floor ~159).
__global__ __launch_bounds__(BT)
void fused_kernel(const float* __restrict__ x,
                  const float* __restrict__ weight,
                  const float* __restrict__ bias,
                  const int* __restrict__ gstart,
                  const int* __restrict__ gend,
                  float* __restrict__ out) {
    __shared__ h2 tile[LDS_ROWS * 64];   // [row][lo-plane 0..31 | hi-plane 32..63]
    __shared__ float lsum, lss;

    const int lane32 = threadIdx.x & 31;
    const int grp    = threadIdx.x >> 5;   // 0..15

    const int g = blockIdx.x;              // one graph per block
    const int s = gstart[g];
    const int e = gend[g];
    if (s >= e) return;                    // uniform across block

    if (threadIdx.x == 0) { lsum = 0.0f; lss = 0.0f; }
    __syncthreads();

    const f4 w = reinterpret_cast<const f4*>(weight)[lane32];
    const f4 b = reinterpret_cast<const f4*>(bias)[lane32];

    float as0 = 0.0f, ass0 = 0.0f, as1 = 0.0f, ass1 = 0.0f;

    // ---- sweep 1a: rows [s, s+304) -> LDS fp16 tile (NT: single HBM touch) ----
    #pragma unroll
    for (int j = 0; j < LDS_IT; ++j) {
        const int slot = j * NGRP + grp;
        const int rr = s + slot;
        const bool valid = rr < e;
        const int r = valid ? rr : (e - 1);
        const float m = valid ? 1.0f : 0.0f;
        const f4 v = LOADX_NT(r);
        tile[slot * 64 + lane32]      = __builtin_amdgcn_cvt_pkrtz(v.x, v.y);
        tile[slot * 64 + 32 + lane32] = __builtin_amdgcn_cvt_pkrtz(v.z, v.w);
        ROWSTAT(v, j & 1);
    }

    // ---- sweep 1b: rows [s+304, s+720) -> fp16 register tile ----
    h2 hv[2 * RK];                         // 52 VGPRs
    const int rbase = s + LDS_ROWS + grp;
    #pragma unroll
    for (int k = 0; k < RK; ++k) {
        const int rr = rbase + k * NGRP;
        const bool valid = rr < e;
        const int r = valid ? rr : (e - 1);
        const float m = valid ? 1.0f : 0.0f;
        const f4 v = LOADX_NT(r);
        hv[2 * k]     = __builtin_amdgcn_cvt_pkrtz(v.x, v.y);
        hv[2 * k + 1] = __builtin_amdgcn_cvt_pkrtz(v.z, v.w);
        ROWSTAT(v, k & 1);
    }

    // ---- sweep 1c: rows [s+720, e) streamed (PLAIN loads -> L3 for re-read) ----
    {
        const float m = 1.0f;
        int r = s + TILE_ROWS + grp;
        for (; r + 3 * NGRP < e; r += 4 * NGRP) {
            const f4 v0 = LOADX(r);
            const f4 v1 = LOADX(r + NGRP);
            const f4 v2 = LOADX(r + 2 * NGRP);
            const f4 v3 = LOADX(r + 3 * NGRP);
            ROWSTAT(v0, 0); ROWSTAT(v1, 1); ROWSTAT(v2, 0); ROWSTAT(v3, 1);
        }
        for (; r < e; r += NGRP) {
            const f4 v = LOADX(r);
            ROWSTAT(v, 0);
        }
    }

    float as = as0 + as1, ass = ass0 + ass1;
    #pragma unroll
    for (int off = 16; off > 0; off >>= 1) {
        as  += __shfl_down(as,  off, 32);
        ass += __shfl_down(ass, off, 32);
    }
    if (lane32 == 0) {
        atomicAdd(&lsum, as);
        atomicAdd(&lss,  ass);
    }
    __syncthreads();

    // stats computed redundantly by every thread
    const float denom = (float)(e - s) * (float)NUM_FEAT;
    const float mean  = lsum / denom;
    const float var   = fmaxf(lss / denom - mean * mean, 0.0f);
    const float inv   = rsqrtf(var + EPS);
    const float mi    = mean * inv;        // o = w*(v*inv - mi) + b

    // ---- sweep 2a: normalize LDS rows, NT stream out ----
    #pragma unroll
    for (int j = 0; j < LDS_IT; ++j) {
        const int slot = j * NGRP + grp;
        const int rr = s + slot;
        const int r = (rr < e) ? rr : (e - 1);   // clamped dup writes = same bytes
        const h2 a = tile[slot * 64 + lane32];
        const h2 c = tile[slot * 64 + 32 + lane32];
        f4 o;
        o.x = fmaf(w.x, fmaf((float)a.x, inv, -mi), b.x);
        o.y = fmaf(w.y, fmaf((float)a.y, inv, -mi), b.y);
        o.z = fmaf(w.z, fmaf((float)c.x, inv, -mi), b.z);
        o.w = fmaf(w.w, fmaf((float)c.y, inv, -mi), b.w);
        __builtin_nontemporal_store(
            o, &reinterpret_cast<f4*>(out + (size_t)r * NUM_FEAT)[lane32]);
    }

    // ---- sweep 2b: normalize register rows ----
    #pragma unroll
    for (int k = 0; k < RK; ++k) {
        const int rr = rbase + k * NGRP;
        const int r = (rr < e) ? rr : (e - 1);
        const h2 a = hv[2 * k];
        const h2 c = hv[2 * k + 1];
        f4 o;
        o.x = fmaf(w.x, fmaf((float)a.x, inv, -mi), b.x);
        o.y = fmaf(w.y, fmaf((float)a.y, inv, -mi), b.y);
        o.z = fmaf(w.z, fmaf((float)c.x, inv, -mi), b.z);
        o.w = fmaf(w.w, fmaf((float)c.y, inv, -mi), b.w);
        __builtin_nontemporal_store(
            o, &reinterpret_cast<f4*>(out + (size_t)r * NUM_FEAT)[lane32]);
    }

    // ---- sweep 2c: streamed rows re-read from L3 (plain), fp32 exact ----
    {
        int r = s + TILE_ROWS + grp;
        for (; r + 3 * NGRP < e; r += 4 * NGRP) {
            const f4 v0 = LOADX(r);
            const f4 v1 = LOADX(r + NGRP);
            const f4 v2 = LOADX(r + 2 * NGRP);
            const f4 v3 = LOADX(r + 3 * NGRP);
            f4 o0, o1, o2, o3;
            o0.x = fmaf(w.x, fmaf(v0.x, inv, -mi), b.x);
            o0.y = fmaf(w.y, fmaf(v0.y, inv, -mi), b.y);
            o0.z = fmaf(w.z, fmaf(v0.z, inv, -mi), b.z);
            o0.w = fmaf(w.w, fmaf(v0.w, inv, -mi), b.w);
            o1.x = fmaf(w.x, fmaf(v1.x, inv, -mi), b.x);
            o1.y = fmaf(w.y, fmaf(v1.y, inv, -mi), b.y);
            o1.z = fmaf(w.z, fmaf(v1.z, inv, -mi), b.z);
            o1.w = fmaf(w.w, fmaf(v1.w, inv, -mi), b.w);
            o2.x = fmaf(w.x, fmaf(v2.x, inv, -mi), b.x);
            o2.y = fmaf(w.y, fmaf(v2.y, inv, -mi), b.y);
            o2.z = fmaf(w.z, fmaf(v2.z, inv, -mi), b.z);
            o2.w = fmaf(w.w, fmaf(v2.w, inv, -mi), b.w);
            o3.x = fmaf(w.x, fmaf(v3.x, inv, -mi), b.x);
            o3.y = fmaf(w.y, fmaf(v3.y, inv, -mi), b.y);
            o3.z = fmaf(w.z, fmaf(v3.z, inv, -mi), b.z);
            o3.w = fmaf(w.w, fmaf(v3.w, inv, -mi), b.w);
            __builtin_nontemporal_store(o0, &reinterpret_cast<f4*>(out + (size_t)r * NUM_FEAT)[lane32]);
            __builtin_nontemporal_store(o1, &reinterpret_cast<f4*>(out + (size_t)(r + NGRP) * NUM_FEAT)[lane32]);
            __builtin_nontemporal_store(o2, &reinterpret_cast<f4*>(out + (size_t)(r + 2 * NGRP) * NUM_FEAT)[lane32]);
            __builtin_nontemporal_store(o3, &reinterpret_cast<f4*>(out + (size_t)(r + 3 * NGRP) * NUM_FEAT)[lane32]);
        }
        for (; r < e; r += NGRP) {
            const f4 v = LOADX(r);
            f4 o;
            o.x = fmaf(w.x, fmaf(v.x, inv, -mi), b.x);
            o.y = fmaf(w.y, fmaf(v.y, inv, -mi), b.y);
            o.z = fmaf(w.z, fmaf(v.z, inv, -mi), b.z);
            o.w = fmaf(w.w, fmaf(v.w, inv, -mi), b.w);
            __builtin_nontemporal_store(
                o, &reinterpret_cast<f4*>(out + (size_t)r * NUM_FEAT)[lane32]);
        }
    }
}

extern "C" void kernel_launch(void* const* d_in, const int* in_sizes, int n_in,
                              void* d_out, int out_size, void* d_ws, size_t ws_size,
                              hipStream_t stream) {
    const float* x      = (const float*)d_in[0];
    const int*   batch  = (const int*)d_in[1];
    const float* weight = (const float*)d_in[2];
    const float* bias   = (const float*)d_in[3];
    float* out = (float*)d_out;

    const int n_rows = in_sizes[1];  // NUM_NODES

    int* gstart = (int*)d_ws;
    int* gend   = gstart + NUM_GRAPHS;

    init_bounds_kernel<<<(NUM_GRAPHS + 255) / 256, 256, 0, stream>>>(gstart, gend);
    find_bounds_kernel<<<(n_rows + 255) / 256, 256, 0, stream>>>(batch, n_rows,
                                                                 gstart, gend);
    fused_kernel<<<NUM_GRAPHS, BT, 0, stream>>>(x, weight, bias, gstart, gend, out);
}